// Round 13
// baseline (739.569 us; speedup 1.0000x reference)
//
#include <hip/hip_runtime.h>
#include <math.h>

#define Bc 4
#define Nc 512
#define Pc 1024
#define Kc 20
#define MUL 64
#define NBc 20
#define HID 100
#define Tc 3
#define CUTc 4.0f
#define Ec (Nc * Kc)        /* 10240 */
#define PEc (Pc * Kc)       /* 20480 */
#define NA (Bc * Nc)        /* 2048 */
#define NP (Bc * Pc)        /* 4096 */
#define ET (Bc * Ec)        /* 40960 */
#define PET (Bc * PEc)      /* 81920 */
#define TBL 1024            /* w-table points over r in [0, RMAXT] */
#define RMAXT 5.25f         /* rbf(r) dead beyond ~5 (centers end 4.0, sigma 0.2) */
#define CAP 64              /* bucket capacity per dst (max degree ~38 expected) */
#define TROWS 4             /* table rows emitted per block in front_kernel */
#define TBLOCKS (6 * TBL / TROWS)  /* 1536 */
#define ZBLOCKS 8
#define EBLOCKS 32

__device__ __forceinline__ float silu_f(float x) { return x / (1.0f + __expf(-x)); }
__device__ __forceinline__ float lane_bcast_f(float v, int l) {
    return __int_as_float(__builtin_amdgcn_readlane(__float_as_int(v), l));
}

// ---------------------------------------------------------------------------
// Front kernel — all dep-free work at FULL grid width (lessons: r8 never
// narrow the grid when fusing; r10 never grid.sync on MI355X):
//   blocks [0,1536):   w-table as (w, dw) float2; TROWS rows/block (+1 overlap)
//   blocks [1536,1544): zero cnt arrays (runtime fill kernel costs 41us)
//   blocks [1544,1576): embedding row 0
// ---------------------------------------------------------------------------
__global__ __launch_bounds__(256) void front_kernel(
    const float* __restrict__ Wr1, const float* __restrict__ pWr1,
    const float* __restrict__ br1, const float* __restrict__ pbr1,
    const float* __restrict__ Wr2, const float* __restrict__ pWr2,
    const float* __restrict__ br2, const float* __restrict__ pbr2,
    const int* __restrict__ nodes, const float* __restrict__ Wemb,
    int* __restrict__ cnt_both, float* __restrict__ h0row,
    float2* __restrict__ wtab)       // (6*TBL, 64) of (w, w_next - w)
{
    __shared__ float Hs[(TROWS + 1) * HID];   // 2.0 KB
    __shared__ float Ws[(TROWS + 1) * MUL];   // 1.25 KB
    int bid = blockIdx.x;
    int t = threadIdx.x;

    if (bid < TBLOCKS) {
        int grow0 = bid * TROWS;          // global table row base (same ly for all)
        int ly = grow0 / TBL;
        int rin = grow0 % TBL;            // row within layer
        int t3 = (ly < 3) ? ly : ly - 3;
        const float* w1 = ((ly < 3) ? Wr1 : pWr1) + (size_t)t3 * NBc * HID;
        const float* b1 = ((ly < 3) ? br1 : pbr1) + (size_t)t3 * HID;
        const float* w2 = ((ly < 3) ? Wr2 : pWr2) + (size_t)t3 * HID * MUL;
        const float* b2 = ((ly < 3) ? br2 : pbr2) + (size_t)t3 * MUL;
        const float step = CUTc / (NBc - 1);
        const float inv_sigma = (float)NBc / CUTc;

        // phase A: hidden for TROWS+1 rows (last row only feeds dw)
        for (int id = t; id < (TROWS + 1) * HID; id += 256) {
            int il = id / HID, j = id - il * HID;
            float r = (float)(rin + il) * (RMAXT / (float)TBL);
            float s = b1[j];
#pragma unroll
            for (int k = 0; k < NBc; ++k) {
                float tt = (r - k * step) * inv_sigma;
                s = fmaf(__expf(-tt * tt), w1[k * HID + j], s);
            }
            Hs[id] = silu_f(s);
        }
        __syncthreads();

        // phase B1: w values for TROWS+1 rows (LDS broadcast + L1 W2 rows)
        for (int id = t; id < (TROWS + 1) * MUL; id += 256) {
            int il = id >> 6, c = id & 63;
            float acc = b2[c];
#pragma unroll 4
            for (int j = 0; j < HID; ++j)
                acc = fmaf(Hs[il * HID + j], w2[(size_t)j * MUL + c], acc);
            Ws[id] = acc;
        }
        __syncthreads();

        // phase B2: emit (w, dw)
        {
            int il = t >> 6, c = t & 63;
            float w0 = Ws[il * MUL + c];
            float w1v = Ws[(il + 1) * MUL + c];
            wtab[(size_t)(grow0 + il) * MUL + c] = make_float2(w0, w1v - w0);
        }
    } else if (bid < TBLOCKS + ZBLOCKS) {
        int idx = (bid - TBLOCKS) * 256 + t;
        for (int i = idx; i < NA + NP; i += ZBLOCKS * 256) cnt_both[i] = 0;
    } else {
        int idx = (bid - TBLOCKS - ZBLOCKS) * 256 + t;
        for (int i = idx; i < NA * MUL; i += EBLOCKS * 256) {
            int a = i >> 6, c = i & 63;
            h0row[i] = Wemb[nodes[a] * MUL + c];
        }
    }
}

// ---------------------------------------------------------------------------
// Geometry + bucket fill (both graphs, one launch). Fixed CAP=64 slots/dst.
// ---------------------------------------------------------------------------
__global__ void geom_kernel(const float* __restrict__ apos,
                            const float* __restrict__ ppos,
                            const int* __restrict__ a_edges,
                            const int* __restrict__ p_edges,
                            const float* __restrict__ a_disp,
                            const float* __restrict__ p_disp,
                            const float* __restrict__ cell,
                            int* __restrict__ cnt_a, int* __restrict__ cnt_p,
                            float* __restrict__ br_a, int* __restrict__ bs_a,
                            float* __restrict__ br_p, int* __restrict__ bs_p)
{
    int e = blockIdx.x * 256 + threadIdx.x;
    if (e >= ET + PET) return;
    const int* edges; const float* displ; const float* pdst;
    int* cnt; float* brout; int* bsout;
    int el, Eper, dst_stride;
    if (e < ET) {
        el = e; edges = a_edges; displ = a_disp; pdst = apos;
        Eper = Ec; dst_stride = Nc; cnt = cnt_a; brout = br_a; bsout = bs_a;
    } else {
        el = e - ET; edges = p_edges; displ = p_disp; pdst = ppos;
        Eper = PEc; dst_stride = Pc; cnt = cnt_p; brout = br_p; bsout = bs_p;
    }
    int b = el / Eper;
    int sg = edges[el * 2 + 0] + b * Nc;
    int dg = edges[el * 2 + 1] + b * dst_stride;
    const float* C = cell + b * 9;
    float d0 = displ[el * 3 + 0], d1 = displ[el * 3 + 1], d2 = displ[el * 3 + 2];
    float dx = d0 * C[0] + d1 * C[3] + d2 * C[6];
    float dy = d0 * C[1] + d1 * C[4] + d2 * C[7];
    float dz = d0 * C[2] + d1 * C[5] + d2 * C[8];
    float vx = pdst[dg * 3 + 0] - (apos[sg * 3 + 0] + dx);
    float vy = pdst[dg * 3 + 1] - (apos[sg * 3 + 1] + dy);
    float vz = pdst[dg * 3 + 2] - (apos[sg * 3 + 2] + dz);
    float r = sqrtf(vx * vx + vy * vy + vz * vz);
    int pos = atomicAdd(&cnt[dg], 1);
    if (pos < CAP) {
        brout[(size_t)dg * CAP + pos] = r;
        bsout[(size_t)dg * CAP + pos] = sg;
    }
}

// ---------------------------------------------------------------------------
// ALL THREE atom layers in one launch. The atom graph is batch-local (src and
// dst share the +b*N offset), so block b owns batch b's 512 nodes completely:
// layer t+1's gather only needs rep_t of nodes written by THIS block.
// Block = 1024 threads = 16 waves x 32 nodes. Block barrier between layers
// (cheap, unlike grid.sync - round-10 lesson). Wl0 column staged in VGPRs.
// ---------------------------------------------------------------------------
__global__ __launch_bounds__(1024, 1) void atom3_kernel(
    const float* __restrict__ h0row,  // (NA,64)
    float* __restrict__ rep0, float* __restrict__ rep1, float* __restrict__ rep2,
    const int* __restrict__ cnt,
    const float* __restrict__ brk, const int* __restrict__ bsk,
    const float2* __restrict__ wtab,  // (3,TBL,64) atom tables
    const float* __restrict__ Wl)     // (3,3,64,64); l0 slice per layer
{
    __shared__ float tile[16][64];
    int b = blockIdx.x;
    int t = threadIdx.x;
    int c = t & 63;
    int w = t >> 6;                    // 0..15
    int n0 = b * Nc + w * 32;          // this wave's first node
    const float scale = (float)TBL / RMAXT;
    const float isk = 0.22360679774997896f;  // 1/sqrt(20)

    const float* hprev = h0row;
    float* reps[3] = {rep0, rep1, rep2};
    for (int tl = 0; tl < Tc; ++tl) {
        const float2* wt = wtab + (size_t)tl * TBL * MUL;
        const float* W = Wl + (size_t)tl * 3 * MUL * MUL;
        float wcol[64];                // staged once, used 32x
#pragma unroll
        for (int k = 0; k < 64; ++k) wcol[k] = W[k * 64 + c];
        float* outb = reps[tl];

        for (int i = 0; i < 32; ++i) {
            int n = n0 + i;
            int m = min(cnt[n], CAP);
            float rvec = 0.0f; int svec = 0;
            if (c < m) { rvec = brk[(size_t)n * CAP + c]; svec = bsk[(size_t)n * CAP + c]; }
            float acc = 0.0f;
#pragma unroll 4
            for (int p = 0; p < m; ++p) {
                float rr = lane_bcast_f(rvec, p);
                int sg = __builtin_amdgcn_readlane(svec, p);
                float x = fminf(rr * scale, (float)TBL - 1.001f);
                int i0 = (int)x;
                float f = x - (float)i0;
                float2 v = wt[(size_t)i0 * MUL + c];
                float wvv = fmaf(v.y, f, v.x);
                acc = fmaf(hprev[(size_t)sg * MUL + c], wvv, acc);
            }
            tile[w][c] = acc * isk;    // same-wave LDS RAW; no barrier
            float u = 0.0f;
#pragma unroll
            for (int k4 = 0; k4 < 16; ++k4) {
                float4 av = *(const float4*)&tile[w][k4 * 4];
                u = fmaf(av.x, wcol[k4 * 4 + 0], u);
                u = fmaf(av.y, wcol[k4 * 4 + 1], u);
                u = fmaf(av.z, wcol[k4 * 4 + 2], u);
                u = fmaf(av.w, wcol[k4 * 4 + 3], u);
            }
            outb[(size_t)n * MUL + c] = hprev[(size_t)n * MUL + c] + silu_f(u);
        }
        __threadfence_block();         // make this block's global writes visible
        __syncthreads();               // to all its waves before the next layer
        hprev = outb;
    }
}

// ---------------------------------------------------------------------------
// Fused probe pipeline (round-11 measured-best form, float2 table):
// 3 probe conv layers + readout, wave per node, 4 waves/block.
// ---------------------------------------------------------------------------
__global__ __launch_bounds__(256) void probe3_kernel(
    const float* __restrict__ rep0, const float* __restrict__ rep1,
    const float* __restrict__ rep2,
    const int* __restrict__ cnt,
    const float* __restrict__ brk, const int* __restrict__ bsk,
    const float2* __restrict__ wtab,  // probe tables base (3 x TBL x 64)
    const float* __restrict__ pWl,    // (3,3,64,64); l0 slice per t
    const float* __restrict__ Wout,   // (64)
    float* __restrict__ out)          // (NP)
{
    __shared__ float tile[4][64];
    int c = threadIdx.x & 63;
    int w = threadIdx.x >> 6;
    int n = blockIdx.x * 4 + w;

    int m = min(cnt[n], CAP);
    float rvec = 0.0f; int svec = 0;
    if (c < m) { rvec = brk[(size_t)n * CAP + c]; svec = bsk[(size_t)n * CAP + c]; }
    float acc0 = 0.0f, acc1 = 0.0f, acc2 = 0.0f;
    const float scale = (float)TBL / RMAXT;
    const float2* wt0 = wtab;
    const float2* wt1 = wtab + (size_t)TBL * MUL;
    const float2* wt2 = wtab + (size_t)2 * TBL * MUL;
#pragma unroll 2
    for (int p = 0; p < m; ++p) {
        float rr = lane_bcast_f(rvec, p);
        int sg = __builtin_amdgcn_readlane(svec, p);
        float x = fminf(rr * scale, (float)TBL - 1.001f);
        int i0 = (int)x;
        float f = x - (float)i0;
        size_t rowo = (size_t)i0 * MUL + c;
        float2 v0 = wt0[rowo], v1 = wt1[rowo], v2 = wt2[rowo];
        float wv0 = fmaf(v0.y, f, v0.x);
        float wv1 = fmaf(v1.y, f, v1.x);
        float wv2 = fmaf(v2.y, f, v2.x);
        size_t so = (size_t)sg * MUL + c;
        acc0 = fmaf(rep0[so], wv0, acc0);
        acc1 = fmaf(rep1[so], wv1, acc1);
        acc2 = fmaf(rep2[so], wv2, acc2);
    }
    const float isk = 0.22360679774997896f;  // 1/sqrt(20)
    float res = 0.0f;
    float accs[3] = {acc0, acc1, acc2};
#pragma unroll
    for (int tt = 0; tt < 3; ++tt) {
        tile[w][c] = accs[tt] * isk;          // same-wave LDS RAW
        const float* W = pWl + (size_t)tt * 3 * MUL * MUL;  // l0 slice
        float u = 0.0f;
#pragma unroll
        for (int k4 = 0; k4 < 16; ++k4) {
            float4 av = *(const float4*)&tile[w][k4 * 4];
            u = fmaf(av.x, W[(k4 * 4 + 0) * 64 + c], u);
            u = fmaf(av.y, W[(k4 * 4 + 1) * 64 + c], u);
            u = fmaf(av.z, W[(k4 * 4 + 2) * 64 + c], u);
            u = fmaf(av.w, W[(k4 * 4 + 3) * 64 + c], u);
        }
        res += silu_f(u);
    }

    float v = res * Wout[c];
#pragma unroll
    for (int o = 32; o > 0; o >>= 1) v += __shfl_down(v, o, 64);
    if (c == 0) out[n] = v;
}

// ---------------------------------------------------------------------------
extern "C" void kernel_launch(void* const* d_in, const int* in_sizes, int n_in,
                              void* d_out, int out_size, void* d_ws, size_t ws_size,
                              hipStream_t stream)
{
    const float* atom_xyz  = (const float*)d_in[0];
    const float* a_disp    = (const float*)d_in[1];
    const float* cell      = (const float*)d_in[2];
    const float* probe_xyz = (const float*)d_in[3];
    const float* p_disp    = (const float*)d_in[4];
    const float* W_embed   = (const float*)d_in[5];
    const float* Wr1       = (const float*)d_in[6];
    const float* br1       = (const float*)d_in[7];
    const float* Wr2       = (const float*)d_in[8];
    const float* br2       = (const float*)d_in[9];
    const float* Wl        = (const float*)d_in[10];
    const float* pWr1      = (const float*)d_in[12];
    const float* pbr1      = (const float*)d_in[13];
    const float* pWr2      = (const float*)d_in[14];
    const float* pbr2      = (const float*)d_in[15];
    const float* pWl       = (const float*)d_in[16];
    const float* W_out     = (const float*)d_in[18];
    const int*   atom_edges  = (const int*)d_in[19];
    const int*   probe_edges = (const int*)d_in[20];
    const int*   nodes       = (const int*)d_in[21];
    float* out = (float*)d_out;

    char* w = (char*)d_ws;
    auto alloc = [&](size_t bytes) -> void* {
        void* r = (void*)w;
        w += (bytes + 255) & ~(size_t)255;
        return r;
    };
    int*   cnt_both = (int*)alloc((size_t)(NA + NP) * 4);
    int*   cnt_a  = cnt_both;
    int*   cnt_p  = cnt_both + NA;
    float* br_a   = (float*)alloc((size_t)NA * CAP * 4);
    int*   bs_a   = (int*)alloc((size_t)NA * CAP * 4);
    float* br_p   = (float*)alloc((size_t)NP * CAP * 4);
    int*   bs_p   = (int*)alloc((size_t)NP * CAP * 4);
    float* h0row  = (float*)alloc((size_t)NA * MUL * 4);
    float* rep0   = (float*)alloc((size_t)NA * MUL * 4);
    float* rep1   = (float*)alloc((size_t)NA * MUL * 4);
    float* rep2   = (float*)alloc((size_t)NA * MUL * 4);
    float2* wtab  = (float2*)alloc((size_t)6 * TBL * MUL * 8);

    // 1) dep-free front-end: (w,dw) table + cnt zero + embedding
    front_kernel<<<TBLOCKS + ZBLOCKS + EBLOCKS, 256, 0, stream>>>(
        Wr1, pWr1, br1, pbr1, Wr2, pWr2, br2, pbr2,
        nodes, W_embed, cnt_both, h0row, wtab);

    // 2) geometry + bucket fill
    geom_kernel<<<(ET + PET + 255) / 256, 256, 0, stream>>>(
        atom_xyz, probe_xyz, atom_edges, probe_edges, a_disp, p_disp, cell,
        cnt_a, cnt_p, br_a, bs_a, br_p, bs_p);

    // 3) all three atom layers in one launch (batch-local graph => block=batch)
    atom3_kernel<<<Bc, 1024, 0, stream>>>(
        h0row, rep0, rep1, rep2, cnt_a, br_a, bs_a, wtab, Wl);

    // 4) fused probe layers + readout
    probe3_kernel<<<NP / 4, 256, 0, stream>>>(
        rep0, rep1, rep2, cnt_p, br_p, bs_p,
        wtab + (size_t)3 * TBL * MUL, pWl, W_out, out);
}

// Round 14
// 87.468 us; speedup vs baseline: 8.4553x; 8.4553x over previous
//
#include <hip/hip_runtime.h>
#include <math.h>

#define Bc 4
#define Nc 512
#define Pc 1024
#define Kc 20
#define MUL 64
#define NBc 20
#define HID 100
#define Tc 3
#define CUTc 4.0f
#define Ec (Nc * Kc)        /* 10240 */
#define PEc (Pc * Kc)       /* 20480 */
#define NA (Bc * Nc)        /* 2048 */
#define NP (Bc * Pc)        /* 4096 */
#define ET (Bc * Ec)        /* 40960 */
#define PET (Bc * PEc)      /* 81920 */
#define TBL 1024            /* w-table points over r in [0, RMAXT] */
#define RMAXT 5.25f         /* rbf(r) dead beyond ~5 (r13 showed absmax unchanged) */
#define CAP 64              /* bucket capacity per dst (max degree ~38 expected) */
#define TROWS 4             /* table rows emitted per block in front_kernel */
#define TBLOCKS (6 * TBL / TROWS)  /* 1536 */
#define ZBLOCKS 8
#define EBLOCKS 32

__device__ __forceinline__ float silu_f(float x) { return x / (1.0f + __expf(-x)); }
__device__ __forceinline__ float lane_bcast_f(float v, int l) {
    return __int_as_float(__builtin_amdgcn_readlane(__float_as_int(v), l));
}

// ---------------------------------------------------------------------------
// Front kernel — all dep-free work at FULL grid width (lessons: r8/r13 never
// narrow the grid when fusing; r10 never grid.sync on MI355X):
//   blocks [0,1536):   w-tables; TROWS rows/block (+1 overlap row for dw).
//     atom layers (ly<3):  awtab[ly][row][c] = float2(w, dw)
//     probe layers (ly>=3): packed across t: pw4[row][c]={w0,dw0,w1,dw1},
//                           pw2[row][c]={w2,dw2}
//   blocks [1536,1544): zero cnt arrays (runtime fill kernel costs 41us)
//   blocks [1544,1576): embedding row 0
// ---------------------------------------------------------------------------
__global__ __launch_bounds__(256) void front_kernel(
    const float* __restrict__ Wr1, const float* __restrict__ pWr1,
    const float* __restrict__ br1, const float* __restrict__ pbr1,
    const float* __restrict__ Wr2, const float* __restrict__ pWr2,
    const float* __restrict__ br2, const float* __restrict__ pbr2,
    const int* __restrict__ nodes, const float* __restrict__ Wemb,
    int* __restrict__ cnt_both, float* __restrict__ h0row,
    float2* __restrict__ awtab,      // (3*TBL, 64) atom (w,dw)
    float2* __restrict__ pw4,        // (TBL, 64, 2) halves of float4 {w0,dw0,w1,dw1}
    float2* __restrict__ pw2)        // (TBL, 64) {w2,dw2}
{
    __shared__ float Hs[(TROWS + 1) * HID];   // 2.0 KB
    __shared__ float Ws[(TROWS + 1) * MUL];   // 1.25 KB
    int bid = blockIdx.x;
    int t = threadIdx.x;

    if (bid < TBLOCKS) {
        int grow0 = bid * TROWS;          // global table row base (one ly per block)
        int ly = grow0 / TBL;
        int rin = grow0 % TBL;            // row within layer
        int t3 = (ly < 3) ? ly : ly - 3;
        const float* w1 = ((ly < 3) ? Wr1 : pWr1) + (size_t)t3 * NBc * HID;
        const float* b1 = ((ly < 3) ? br1 : pbr1) + (size_t)t3 * HID;
        const float* w2 = ((ly < 3) ? Wr2 : pWr2) + (size_t)t3 * HID * MUL;
        const float* b2 = ((ly < 3) ? br2 : pbr2) + (size_t)t3 * MUL;
        const float step = CUTc / (NBc - 1);
        const float inv_sigma = (float)NBc / CUTc;

        // phase A: hidden for TROWS+1 rows (last row only feeds dw)
        for (int id = t; id < (TROWS + 1) * HID; id += 256) {
            int il = id / HID, j = id - il * HID;
            float r = (float)(rin + il) * (RMAXT / (float)TBL);
            float s = b1[j];
#pragma unroll
            for (int k = 0; k < NBc; ++k) {
                float tt = (r - k * step) * inv_sigma;
                s = fmaf(__expf(-tt * tt), w1[k * HID + j], s);
            }
            Hs[id] = silu_f(s);
        }
        __syncthreads();

        // phase B1: w values for TROWS+1 rows (LDS broadcast + L1 W2 rows)
        for (int id = t; id < (TROWS + 1) * MUL; id += 256) {
            int il = id >> 6, c = id & 63;
            float acc = b2[c];
#pragma unroll 4
            for (int j = 0; j < HID; ++j)
                acc = fmaf(Hs[il * HID + j], w2[(size_t)j * MUL + c], acc);
            Ws[id] = acc;
        }
        __syncthreads();

        // phase B2: emit (w, dw) into the layout the consumers want
        {
            int il = t >> 6, c = t & 63;
            int row = rin + il;
            float w0 = Ws[il * MUL + c];
            float dw = Ws[(il + 1) * MUL + c] - w0;
            if (ly < 3) {
                awtab[((size_t)ly * TBL + row) * MUL + c] = make_float2(w0, dw);
            } else if (t3 < 2) {
                pw4[((size_t)row * MUL + c) * 2 + t3] = make_float2(w0, dw);
            } else {
                pw2[(size_t)row * MUL + c] = make_float2(w0, dw);
            }
        }
    } else if (bid < TBLOCKS + ZBLOCKS) {
        int idx = (bid - TBLOCKS) * 256 + t;
        for (int i = idx; i < NA + NP; i += ZBLOCKS * 256) cnt_both[i] = 0;
    } else {
        int idx = (bid - TBLOCKS - ZBLOCKS) * 256 + t;
        for (int i = idx; i < NA * MUL; i += EBLOCKS * 256) {
            int a = i >> 6, c = i & 63;
            h0row[i] = Wemb[nodes[a] * MUL + c];
        }
    }
}

// ---------------------------------------------------------------------------
// Geometry + bucket fill (both graphs, one launch). Fixed CAP=64 slots/dst.
// ---------------------------------------------------------------------------
__global__ void geom_kernel(const float* __restrict__ apos,
                            const float* __restrict__ ppos,
                            const int* __restrict__ a_edges,
                            const int* __restrict__ p_edges,
                            const float* __restrict__ a_disp,
                            const float* __restrict__ p_disp,
                            const float* __restrict__ cell,
                            int* __restrict__ cnt_a, int* __restrict__ cnt_p,
                            float* __restrict__ br_a, int* __restrict__ bs_a,
                            float* __restrict__ br_p, int* __restrict__ bs_p)
{
    int e = blockIdx.x * 256 + threadIdx.x;
    if (e >= ET + PET) return;
    const int* edges; const float* displ; const float* pdst;
    int* cnt; float* brout; int* bsout;
    int el, Eper, dst_stride;
    if (e < ET) {
        el = e; edges = a_edges; displ = a_disp; pdst = apos;
        Eper = Ec; dst_stride = Nc; cnt = cnt_a; brout = br_a; bsout = bs_a;
    } else {
        el = e - ET; edges = p_edges; displ = p_disp; pdst = ppos;
        Eper = PEc; dst_stride = Pc; cnt = cnt_p; brout = br_p; bsout = bs_p;
    }
    int b = el / Eper;
    int sg = edges[el * 2 + 0] + b * Nc;
    int dg = edges[el * 2 + 1] + b * dst_stride;
    const float* C = cell + b * 9;
    float d0 = displ[el * 3 + 0], d1 = displ[el * 3 + 1], d2 = displ[el * 3 + 2];
    float dx = d0 * C[0] + d1 * C[3] + d2 * C[6];
    float dy = d0 * C[1] + d1 * C[4] + d2 * C[7];
    float dz = d0 * C[2] + d1 * C[5] + d2 * C[8];
    float vx = pdst[dg * 3 + 0] - (apos[sg * 3 + 0] + dx);
    float vy = pdst[dg * 3 + 1] - (apos[sg * 3 + 1] + dy);
    float vz = pdst[dg * 3 + 2] - (apos[sg * 3 + 2] + dz);
    float r = sqrtf(vx * vx + vy * vy + vz * vz);
    int pos = atomicAdd(&cnt[dg], 1);
    if (pos < CAP) {
        brout[(size_t)dg * CAP + pos] = r;
        bsout[(size_t)dg * CAP + pos] = sg;
    }
}

// ---------------------------------------------------------------------------
// Atom conv layer (row-0 only), wave per node, 4 waves/block (round-11 form).
// hread: strided view of the previous features (h0row stride 1, or rep4
// component stride 4). Writes its component of rep4.
// ---------------------------------------------------------------------------
__global__ __launch_bounds__(256) void layer_kernel(
    const float* __restrict__ hread,  // element i at hread[i*hs]
    int hs,
    float* __restrict__ wrt,          // write at wrt[i*4]
    const int* __restrict__ cnt,
    const float* __restrict__ brk, const int* __restrict__ bsk,
    const float2* __restrict__ wtab,  // (TBL,64) (w,dw)
    const float* __restrict__ Wl0)    // (64,64)
{
    __shared__ float tile[4][64];
    int c = threadIdx.x & 63;
    int w = threadIdx.x >> 6;
    int n = blockIdx.x * 4 + w;

    int m = min(cnt[n], CAP);
    float rvec = 0.0f; int svec = 0;
    if (c < m) { rvec = brk[(size_t)n * CAP + c]; svec = bsk[(size_t)n * CAP + c]; }
    float acc = 0.0f;
    const float scale = (float)TBL / RMAXT;
#pragma unroll 4
    for (int p = 0; p < m; ++p) {
        float rr = lane_bcast_f(rvec, p);
        int sg = __builtin_amdgcn_readlane(svec, p);
        float x = fminf(rr * scale, (float)TBL - 1.001f);
        int i0 = (int)x;
        float f = x - (float)i0;
        float2 v = wtab[(size_t)i0 * MUL + c];
        float wvv = fmaf(v.y, f, v.x);
        acc = fmaf(hread[((size_t)sg * MUL + c) * hs], wvv, acc);
    }
    acc *= 0.22360679774997896f;  // 1/sqrt(20)

    tile[w][c] = acc;             // same-wave LDS RAW; no barrier needed
    float u = 0.0f;
#pragma unroll
    for (int k4 = 0; k4 < 16; ++k4) {
        float4 av = *(const float4*)&tile[w][k4 * 4];
        u = fmaf(av.x, Wl0[(k4 * 4 + 0) * 64 + c], u);
        u = fmaf(av.y, Wl0[(k4 * 4 + 1) * 64 + c], u);
        u = fmaf(av.z, Wl0[(k4 * 4 + 2) * 64 + c], u);
        u = fmaf(av.w, Wl0[(k4 * 4 + 3) * 64 + c], u);
    }
    size_t idx = (size_t)n * MUL + c;
    wrt[idx * 4] = hread[idx * hs] + silu_f(u);
}

// ---------------------------------------------------------------------------
// Fused probe pipeline: 3 probe conv layers + readout, wave per node,
// 4 waves/block. Per edge: ONE float4 rep load + TWO table loads (was 6).
// ---------------------------------------------------------------------------
__global__ __launch_bounds__(256) void probe3_kernel(
    const float4* __restrict__ rep4,  // (NA*64) {rep0,rep1,rep2,pad}
    const int* __restrict__ cnt,
    const float* __restrict__ brk, const int* __restrict__ bsk,
    const float4* __restrict__ pw4,   // (TBL*64) {w0,dw0,w1,dw1}
    const float2* __restrict__ pw2,   // (TBL*64) {w2,dw2}
    const float* __restrict__ pWl,    // (3,3,64,64); l0 slice per t
    const float* __restrict__ Wout,   // (64)
    float* __restrict__ out)          // (NP)
{
    __shared__ float tile[4][64];
    int c = threadIdx.x & 63;
    int w = threadIdx.x >> 6;
    int n = blockIdx.x * 4 + w;

    int m = min(cnt[n], CAP);
    float rvec = 0.0f; int svec = 0;
    if (c < m) { rvec = brk[(size_t)n * CAP + c]; svec = bsk[(size_t)n * CAP + c]; }
    float acc0 = 0.0f, acc1 = 0.0f, acc2 = 0.0f;
    const float scale = (float)TBL / RMAXT;
#pragma unroll 2
    for (int p = 0; p < m; ++p) {
        float rr = lane_bcast_f(rvec, p);
        int sg = __builtin_amdgcn_readlane(svec, p);
        float x = fminf(rr * scale, (float)TBL - 1.001f);
        int i0 = (int)x;
        float f = x - (float)i0;
        size_t rowo = (size_t)i0 * MUL + c;
        float4 v01 = pw4[rowo];
        float2 v2  = pw2[rowo];
        float wv0 = fmaf(v01.y, f, v01.x);
        float wv1 = fmaf(v01.w, f, v01.z);
        float wv2 = fmaf(v2.y,  f, v2.x);
        float4 rv = rep4[(size_t)sg * MUL + c];
        acc0 = fmaf(rv.x, wv0, acc0);
        acc1 = fmaf(rv.y, wv1, acc1);
        acc2 = fmaf(rv.z, wv2, acc2);
    }
    const float isk = 0.22360679774997896f;  // 1/sqrt(20)
    float res = 0.0f;
    float accs[3] = {acc0, acc1, acc2};
#pragma unroll
    for (int tt = 0; tt < 3; ++tt) {
        tile[w][c] = accs[tt] * isk;          // same-wave LDS RAW
        const float* W = pWl + (size_t)tt * 3 * MUL * MUL;  // l0 slice
        float u = 0.0f;
#pragma unroll
        for (int k4 = 0; k4 < 16; ++k4) {
            float4 av = *(const float4*)&tile[w][k4 * 4];
            u = fmaf(av.x, W[(k4 * 4 + 0) * 64 + c], u);
            u = fmaf(av.y, W[(k4 * 4 + 1) * 64 + c], u);
            u = fmaf(av.z, W[(k4 * 4 + 2) * 64 + c], u);
            u = fmaf(av.w, W[(k4 * 4 + 3) * 64 + c], u);
        }
        res += silu_f(u);
    }

    float v = res * Wout[c];
#pragma unroll
    for (int o = 32; o > 0; o >>= 1) v += __shfl_down(v, o, 64);
    if (c == 0) out[n] = v;
}

// ---------------------------------------------------------------------------
extern "C" void kernel_launch(void* const* d_in, const int* in_sizes, int n_in,
                              void* d_out, int out_size, void* d_ws, size_t ws_size,
                              hipStream_t stream)
{
    const float* atom_xyz  = (const float*)d_in[0];
    const float* a_disp    = (const float*)d_in[1];
    const float* cell      = (const float*)d_in[2];
    const float* probe_xyz = (const float*)d_in[3];
    const float* p_disp    = (const float*)d_in[4];
    const float* W_embed   = (const float*)d_in[5];
    const float* Wr1       = (const float*)d_in[6];
    const float* br1       = (const float*)d_in[7];
    const float* Wr2       = (const float*)d_in[8];
    const float* br2       = (const float*)d_in[9];
    const float* Wl        = (const float*)d_in[10];
    const float* pWr1      = (const float*)d_in[12];
    const float* pbr1      = (const float*)d_in[13];
    const float* pWr2      = (const float*)d_in[14];
    const float* pbr2      = (const float*)d_in[15];
    const float* pWl       = (const float*)d_in[16];
    const float* W_out     = (const float*)d_in[18];
    const int*   atom_edges  = (const int*)d_in[19];
    const int*   probe_edges = (const int*)d_in[20];
    const int*   nodes       = (const int*)d_in[21];
    float* out = (float*)d_out;

    char* w = (char*)d_ws;
    auto alloc = [&](size_t bytes) -> void* {
        void* r = (void*)w;
        w += (bytes + 255) & ~(size_t)255;
        return r;
    };
    int*   cnt_both = (int*)alloc((size_t)(NA + NP) * 4);
    int*   cnt_a  = cnt_both;
    int*   cnt_p  = cnt_both + NA;
    float* br_a   = (float*)alloc((size_t)NA * CAP * 4);
    int*   bs_a   = (int*)alloc((size_t)NA * CAP * 4);
    float* br_p   = (float*)alloc((size_t)NP * CAP * 4);
    int*   bs_p   = (int*)alloc((size_t)NP * CAP * 4);
    float* h0row  = (float*)alloc((size_t)NA * MUL * 4);
    float* rep4   = (float*)alloc((size_t)NA * MUL * 16);   // float4 packed reps
    float2* awtab = (float2*)alloc((size_t)3 * TBL * MUL * 8);
    float2* pw4   = (float2*)alloc((size_t)TBL * MUL * 16); // float4 as 2x float2
    float2* pw2   = (float2*)alloc((size_t)TBL * MUL * 8);

    // 1) dep-free front-end: tables + cnt zero + embedding
    front_kernel<<<TBLOCKS + ZBLOCKS + EBLOCKS, 256, 0, stream>>>(
        Wr1, pWr1, br1, pbr1, Wr2, pWr2, br2, pbr2,
        nodes, W_embed, cnt_both, h0row, awtab, pw4, pw2);

    // 2) geometry + bucket fill
    geom_kernel<<<(ET + PET + 255) / 256, 256, 0, stream>>>(
        atom_xyz, probe_xyz, atom_edges, probe_edges, a_disp, p_disp, cell,
        cnt_a, cnt_p, br_a, bs_a, br_p, bs_p);

    // 3-5) atom layers (round-11 structure; rep4 component writes)
    for (int t = 0; t < Tc; ++t) {
        const float* hread = (t == 0) ? h0row : (rep4 + (t - 1));
        int hs = (t == 0) ? 1 : 4;
        layer_kernel<<<NA / 4, 256, 0, stream>>>(
            hread, hs, rep4 + t, cnt_a, br_a, bs_a,
            awtab + (size_t)t * TBL * MUL,
            Wl + (size_t)t * 3 * MUL * MUL);
    }

    // 6) fused probe layers + readout (packed loads)
    probe3_kernel<<<NP / 4, 256, 0, stream>>>(
        (const float4*)rep4, cnt_p, br_p, bs_p,
        (const float4*)pw4, pw2, pWl, W_out, out);
}